// Round 4
// baseline (252.655 us; speedup 1.0000x reference)
//
#include <hip/hip_runtime.h>

// Output layout (flat, reference return order), N=64, B=16, D=512:
//   [0,       mapsz)          boundary [B,D,N,N]
//   [mapsz, 2*mapsz)          content  [B,D,N,N]
//   [2*mapsz, 2*mapsz+B*N*N)  mask     [B,1,N,N] (0.0/1.0 f32)
//
// Identities (verified R1-R3): on member lines content[i,j] = max(x[i..j]),
// boundary[i,j] = 0.5*(x[i]+x[j]); the diagonal is the len=1 case of both.
//
// R4 structure: one wave handles FOUR tiles. Lane = (group g = lane>>4) x
// (column quad cq = 4*(lane&15)); group g owns tile t0+g. Each row iteration
// writes one full row of 4 tiles as two global_store_dwordx4 (1 KB/instr).
// x[i] per group via ds_bpermute; running max uses a diagonal reset so no
// +-inf guards are needed. No LDS buffers, no barriers.

__global__ __launch_bounds__(256) void sbc_kernel(const float* __restrict__ x,
                                                  float* __restrict__ out,
                                                  size_t mapsz) {
    const int lane = threadIdx.x & 63;
    const int wid  = blockIdx.x * 4 + (threadIdx.x >> 6);
    const int g    = lane >> 4;            // tile index within the wave's group
    const int cq   = (lane & 15) << 2;     // first of this lane's 4 columns
    const int t0   = wid << 2;
    const int tile = t0 + g;

    // Per-column membership masks: bit i set iff (i, c) is on the sparse mask.
    // Same bit-reversed constants as R3 (correctness-verified).
    unsigned long long mb[4];
#pragma unroll
    for (int q = 0; q < 4; ++q) {
        const int j  = cq + q;
        const int sh = 63 - j;
        mb[q] = (1ULL << j)
              | (0x7FFF000000000000ULL >> sh)
              | ((0x0000555500000000ULL >> sh) & 0x5555555555555555ULL)
              | ((0x0000000011111111ULL >> sh) & 0x1111111111111111ULL);
    }

    // This lane's 4 x-values (its columns, its tile): one dwordx4 load.
    const float4 xq = *(const float4*)(x + (size_t)tile * 64 + cq);
    const float xc[4] = {xq.x, xq.y, xq.z, xq.w};
    float r[4] = {xq.x, xq.y, xq.z, xq.w};   // finite init; reset at diagonal

    float* __restrict__ bout = out + (size_t)tile * 4096 + cq;
    float* __restrict__ cout = bout + mapsz;

    const int gbase = (lane & 48) << 2;    // byte index of group's lane 0 in wave

#pragma unroll
    for (int i = 63; i >= 0; --i) {
        // broadcast x[i] of this group's tile: held by lane g*16 + i/4, comp i%4
        const int src = gbase + (i & ~3);  // ((g*16 + (i>>2)) * 4) bytes
        const int comp = i & 3;
        const float xi = __int_as_float(__builtin_amdgcn_ds_bpermute(
            src, __float_as_int(comp == 0 ? xq.x : comp == 1 ? xq.y
                              : comp == 2 ? xq.z : xq.w)));

        float b[4], c[4];
#pragma unroll
        for (int q = 0; q < 4; ++q) {
            const float f = fmaxf(r[q], xi);
            if (q == (i & 3)) {
                // diagonal reset: kills below-diagonal pollution exactly at i==c
                r[q] = (cq == (i & ~3)) ? xc[q] : f;
            } else {
                r[q] = f;
            }
            const bool on = (mb[q] >> i) & 1ULL;
            b[q] = on ? 0.5f * (xi + xc[q]) : 0.0f;
            c[q] = on ? r[q] : 0.0f;
        }
        *(float4*)(bout + i * 64) = make_float4(b[0], b[1], b[2], b[3]);
        *(float4*)(cout + i * 64) = make_float4(c[0], c[1], c[2], c[3]);
    }

    // mask: one tile per batch, owned by the wave whose t0 is a d==0 tile
    // (t0 = b*512, always group 0). Group 0's 16 lanes write it.
    if (((t0 & 511) == 0) && g == 0) {
        float* __restrict__ mout = out + 2 * mapsz + (size_t)(t0 >> 9) * 4096 + cq;
#pragma unroll
        for (int i = 0; i < 64; ++i) {
            float m[4];
#pragma unroll
            for (int q = 0; q < 4; ++q)
                m[q] = ((mb[q] >> i) & 1ULL) ? 1.0f : 0.0f;
            *(float4*)(mout + i * 64) = make_float4(m[0], m[1], m[2], m[3]);
        }
    }
}

extern "C" void kernel_launch(void* const* d_in, const int* in_sizes, int n_in,
                              void* d_out, int out_size, void* d_ws, size_t ws_size,
                              hipStream_t stream) {
    const float* x = (const float*)d_in[0];
    float* out = (float*)d_out;
    const int N  = 64;
    const int BD = in_sizes[0] / N;              // 8192 tiles
    const size_t mapsz = (size_t)BD * N * N;     // 33,554,432
    const int blocks = BD / 16;                  // 4 tiles/wave * 4 waves/block
    sbc_kernel<<<dim3(blocks), dim3(256), 0, stream>>>(x, out, mapsz);
}